// Round 8
// baseline (55.335 us; speedup 1.0000x reference)
//
#include <hip/hip_runtime.h>

typedef float f32x2 __attribute__((ext_vector_type(2)));
typedef float f32x16 __attribute__((ext_vector_type(16)));
typedef __bf16 bf16x8 __attribute__((ext_vector_type(8)));

static __device__ __forceinline__ unsigned short f2bf(float v) {
    unsigned u = __builtin_bit_cast(unsigned, v);
    unsigned r = (u + 0x7FFFu + ((u >> 16) & 1u)) >> 16;
    return (unsigned short)r;
}
static __device__ __forceinline__ bf16x8 ldg8(const unsigned short* p) {
    uint4 u = *(const uint4*)p;
    return __builtin_bit_cast(bf16x8, u);
}
static __device__ __forceinline__ f32x16 mfma32(bf16x8 a, bf16x8 b, f32x16 c) {
    return __builtin_amdgcn_mfma_f32_32x32x16_bf16(a, b, c, 0, 0, 0);
}

// ---------------------------------------------------------------------------
// prep_M: simulate the 64 basis states for each f -> M_f (64x64 complex),
// bf16, layout [f][re/im][d][k]. (verified R1-R7)
// ---------------------------------------------------------------------------
__global__ __launch_bounds__(256) void prep_M(const float* __restrict__ wts,
                                              unsigned short* __restrict__ Mhi) {
    __shared__ float gls[12][8];
    const int f = blockIdx.x >> 4;
    const int tid = threadIdx.x;
    if (tid < 12) {
        int l = tid / 6, w = tid % 6;
        const float* p = wts + ((f * 2 + l) * 6 + w) * 3;
        float phi = p[0], theta = p[1], omega = p[2];
        float c, s; sincosf(0.5f * theta, &s, &c);
        float sapo, capo, samo, camo;
        sincosf(0.5f * (phi + omega), &sapo, &capo);
        sincosf(0.5f * (phi - omega), &samo, &camo);
        float* o = gls[tid];
        o[0] =  capo * c;  o[1] = -sapo * c;
        o[2] = -camo * s;  o[3] = -samo * s;
        o[4] =  camo * s;  o[5] = -samo * s;
        o[6] =  capo * c;  o[7] =  sapo * c;
    }
    __syncthreads();

    const int lane = tid & 63;
    const int wid  = tid >> 6;
    const int bas  = (blockIdx.x & 15) * 4 + wid;

    int src0 = lane, src1 = lane;
#pragma unroll
    for (int w = 5; w >= 0; --w) { int tq = (w + 1) % 6; src0 ^= ((src0 >> (5 - w)) & 1) << (5 - tq); }
#pragma unroll
    for (int w = 5; w >= 0; --w) { int tq = (w + 2) % 6; src1 ^= ((src1 >> (5 - w)) & 1) << (5 - tq); }

    float ar = (lane == bas) ? 1.0f : 0.0f, ai = 0.0f;
#pragma unroll
    for (int rep = 0; rep < 2; ++rep) {
#pragma unroll
        for (int l = 0; l < 2; ++l) {
#pragma unroll
            for (int w = 0; w < 6; ++w) {
                const float* gp = gls[l * 6 + w];
                const float4 uA = *(const float4*)gp;
                const float4 uB = *(const float4*)(gp + 4);
                const int m = 32 >> w;
                const float br = __shfl_xor(ar, m);
                const float bi = __shfl_xor(ai, m);
                const bool hi = (lane & m) != 0;
                const float cmr = hi ? uB.z : uA.x;
                const float cmi = hi ? uB.w : uA.y;
                const float cpr = hi ? uB.x : uA.z;
                const float cpi = hi ? uB.y : uA.w;
                const float nr = cmr * ar - cmi * ai + cpr * br - cpi * bi;
                const float ni = cmr * ai + cmi * ar + cpr * bi + cpi * br;
                ar = nr; ai = ni;
            }
            const int src = l ? src1 : src0;
            ar = __shfl(ar, src);
            ai = __shfl(ai, src);
        }
    }
    Mhi[((f * 2 + 0) * 64 + lane) * 64 + bas] = f2bf(ar);
    Mhi[((f * 2 + 1) * 64 + lane) * 64 + bas] = f2bf(ai);
}

// ---------------------------------------------------------------------------
// Main: zero LDS, zero barriers. Each wave: 32 patches, all 64 d, all 4 f.
// Lane (pc,hi5): B = channel ks, row-pair hi5 of patch pc, loaded from x.
// 128 MFMAs/wave in f-paired dual chains; Z completes with one shfl_xor(32).
// ---------------------------------------------------------------------------
__global__ __launch_bounds__(256, 4) void qconv_main(
        const float* __restrict__ x,
        const unsigned short* __restrict__ Mhi,
        float* __restrict__ out) {
    const int tid  = threadIdx.x;
    const int lane = tid & 63;
    const int w    = tid >> 6;
    const int pc   = lane & 31;
    const int hi5  = lane >> 5;

    const int n   = blockIdx.x * 128 + w * 32 + pc;
    const int b   = n / 961;
    const int pos = n - b * 961;
    const int i   = pos / 31;
    const int j   = pos - i * 31;

    // ---- front-end: 32 elems/lane straight from x ----
    // chunk (2ks+hi5) = channel ks, rows i*2+2*hi5 .. +1, cols j*2 .. +3
    float v[4][8];
    const float* xb = x + ((b * 4) * 64 + (i * 2 + hi5 * 2)) * 64 + j * 2;
#pragma unroll
    for (int ch = 0; ch < 4; ++ch) {
        const float* r0 = xb + ch * 4096;
        *(f32x2*)&v[ch][0] = *(const f32x2*)r0;
        *(f32x2*)&v[ch][2] = *(const f32x2*)(r0 + 2);
        *(f32x2*)&v[ch][4] = *(const f32x2*)(r0 + 64);
        *(f32x2*)&v[ch][6] = *(const f32x2*)(r0 + 66);
    }
    float ss = 0.f;
#pragma unroll
    for (int ch = 0; ch < 4; ++ch)
#pragma unroll
        for (int k = 0; k < 8; ++k) ss += v[ch][k] * v[ch][k];
    ss += __shfl_xor(ss, 32);      // partner lane holds the other half-patch
    const float rn = rsqrtf(ss);

    bf16x8 B[4];
#pragma unroll
    for (int ch = 0; ch < 4; ++ch)
#pragma unroll
        for (int k = 0; k < 8; ++k) B[ch][k] = (__bf16)(v[ch][k] * rn);

    // A-row base: reim from lane bit4, d-offset lane&15, k-offset hi5*8
    const int abase = ((lane >> 4) & 1) * 4096 + (lane & 15) * 64 + hi5 * 8;
    float* const obase = out + b * 24 * 961 + pos;

#pragma unroll 1
    for (int fp = 0; fp < 2; ++fp) {
        float zS0 = 0.f, za0 = 0.f, zb0 = 0.f, z20 = 0.f, z40 = 0.f, z50 = 0.f;
        float zS1 = 0.f, za1 = 0.f, zb1 = 0.f, z21 = 0.f, z41 = 0.f, z51 = 0.f;
#pragma unroll
        for (int dq = 0; dq < 4; ++dq) {
            const int off0 = (fp * 2 + 0) * 8192 + abase + dq * 1024;
            const int off1 = (fp * 2 + 1) * 8192 + abase + dq * 1024;
            bf16x8 Aa[4], Ab[4];
#pragma unroll
            for (int ks = 0; ks < 4; ++ks) {
                Aa[ks] = ldg8(Mhi + off0 + ks * 16);
                Ab[ks] = ldg8(Mhi + off1 + ks * 16);
            }
            f32x16 C0, C1;
#pragma unroll
            for (int r = 0; r < 16; ++r) { C0[r] = 0.f; C1[r] = 0.f; }
#pragma unroll
            for (int ks = 0; ks < 4; ++ks) {
                C0 = mfma32(Aa[ks], B[ks], C0);
                C1 = mfma32(Ab[ks], B[ks], C1);
            }
#pragma unroll
            for (int fo = 0; fo < 2; ++fo) {
                const f32x16 Cv = fo ? C1 : C0;
                float P[8];
#pragma unroll
                for (int r = 0; r < 8; ++r) P[r] = Cv[r] * Cv[r] + Cv[r + 8] * Cv[r + 8];
                const float e0 = P[0] + P[1], o0 = P[0] - P[1];
                const float e1 = P[2] + P[3], o1 = P[2] - P[3];
                const float e2 = P[4] + P[5], o2 = P[4] - P[5];
                const float e3 = P[6] + P[7], o3 = P[6] - P[7];
                const float s01 = e0 + e1, s23 = e2 + e3;
                const float S  = s01 + s23;
                const float Z2 = s01 - s23;               // d bit3 = r>>2
                const float Z4 = (e0 - e1) + (e2 - e3);   // d bit1
                const float Z5 = o0 + o1 + o2 + o3;       // d bit0
                if (fo == 0) {
                    zS0 += S;
                    za0 += (dq & 2) ? -S : S;             // q0: d bit5
                    zb0 += (dq & 1) ? -S : S;             // q1: d bit4
                    z20 += Z2; z40 += Z4; z50 += Z5;
                } else {
                    zS1 += S;
                    za1 += (dq & 2) ? -S : S;
                    zb1 += (dq & 1) ? -S : S;
                    z21 += Z2; z41 += Z4; z51 += Z5;
                }
            }
        }
#pragma unroll
        for (int fo = 0; fo < 2; ++fo) {
            float z0 = fo ? za1 : za0;
            float z1 = fo ? zb1 : zb0;
            float z2 = fo ? z21 : z20;
            float zS = fo ? zS1 : zS0;
            float z4 = fo ? z41 : z40;
            float z5 = fo ? z51 : z50;
            float z3 = hi5 ? -zS : zS;                    // q3: d bit2 = hi5
            z0 += __shfl_xor(z0, 32);
            z1 += __shfl_xor(z1, 32);
            z2 += __shfl_xor(z2, 32);
            z3 += __shfl_xor(z3, 32);
            z4 += __shfl_xor(z4, 32);
            z5 += __shfl_xor(z5, 32);
            float* o = obase + (fp * 2 + fo) * 6 * 961;
            if (hi5 == 0) {
                o[0]        = z0;
                o[961]      = z1;
                o[2 * 961]  = z2;
            } else {
                o[3 * 961]  = z3;
                o[4 * 961]  = z4;
                o[5 * 961]  = z5;
            }
        }
    }
}

extern "C" void kernel_launch(void* const* d_in, const int* in_sizes, int n_in,
                              void* d_out, int out_size, void* d_ws, size_t ws_size,
                              hipStream_t stream) {
    const float* x   = (const float*)d_in[0];   // (128, 4, 64, 64)
    const float* wts = (const float*)d_in[1];   // (4, 2, 6, 3)
    float* out = (float*)d_out;                 // (128, 24, 31, 31)

    unsigned short* Mhi = (unsigned short*)d_ws;

    prep_M<<<64, 256, 0, stream>>>(wts, Mhi);

    const int npatch = 128 * 31 * 31;           // 123008 = 961 * 128
    qconv_main<<<npatch / 128, 256, 0, stream>>>(x, Mhi, out);
}

// Round 9
// 38.732 us; speedup vs baseline: 1.4287x; 1.4287x over previous
//
#include <hip/hip_runtime.h>

typedef float f32x2 __attribute__((ext_vector_type(2)));
typedef float f32x16 __attribute__((ext_vector_type(16)));
typedef __bf16 bf16x8 __attribute__((ext_vector_type(8)));

static __device__ __forceinline__ unsigned short f2bf(float v) {
    unsigned u = __builtin_bit_cast(unsigned, v);
    unsigned r = (u + 0x7FFFu + ((u >> 16) & 1u)) >> 16;
    return (unsigned short)r;
}
static __device__ __forceinline__ bf16x8 ldg8(const unsigned short* p) {
    uint4 u = *(const uint4*)p;
    return __builtin_bit_cast(bf16x8, u);
}
static __device__ __forceinline__ f32x16 mfma32(bf16x8 a, bf16x8 b, f32x16 c) {
    return __builtin_amdgcn_mfma_f32_32x32x16_bf16(a, b, c, 0, 0, 0);
}

// ---------------------------------------------------------------------------
// prep_M: simulate the 64 basis states for each f -> M_f (64x64 complex),
// bf16, layout [f][re/im][d][k]. (verified R1-R8)
// ---------------------------------------------------------------------------
__global__ __launch_bounds__(256) void prep_M(const float* __restrict__ wts,
                                              unsigned short* __restrict__ Mhi) {
    __shared__ float gls[12][8];
    const int f = blockIdx.x >> 4;
    const int tid = threadIdx.x;
    if (tid < 12) {
        int l = tid / 6, w = tid % 6;
        const float* p = wts + ((f * 2 + l) * 6 + w) * 3;
        float phi = p[0], theta = p[1], omega = p[2];
        float c, s; sincosf(0.5f * theta, &s, &c);
        float sapo, capo, samo, camo;
        sincosf(0.5f * (phi + omega), &sapo, &capo);
        sincosf(0.5f * (phi - omega), &samo, &camo);
        float* o = gls[tid];
        o[0] =  capo * c;  o[1] = -sapo * c;
        o[2] = -camo * s;  o[3] = -samo * s;
        o[4] =  camo * s;  o[5] = -samo * s;
        o[6] =  capo * c;  o[7] =  sapo * c;
    }
    __syncthreads();

    const int lane = tid & 63;
    const int wid  = tid >> 6;
    const int bas  = (blockIdx.x & 15) * 4 + wid;

    int src0 = lane, src1 = lane;
#pragma unroll
    for (int w = 5; w >= 0; --w) { int tq = (w + 1) % 6; src0 ^= ((src0 >> (5 - w)) & 1) << (5 - tq); }
#pragma unroll
    for (int w = 5; w >= 0; --w) { int tq = (w + 2) % 6; src1 ^= ((src1 >> (5 - w)) & 1) << (5 - tq); }

    float ar = (lane == bas) ? 1.0f : 0.0f, ai = 0.0f;
#pragma unroll
    for (int rep = 0; rep < 2; ++rep) {
#pragma unroll
        for (int l = 0; l < 2; ++l) {
#pragma unroll
            for (int w = 0; w < 6; ++w) {
                const float* gp = gls[l * 6 + w];
                const float4 uA = *(const float4*)gp;
                const float4 uB = *(const float4*)(gp + 4);
                const int m = 32 >> w;
                const float br = __shfl_xor(ar, m);
                const float bi = __shfl_xor(ai, m);
                const bool hi = (lane & m) != 0;
                const float cmr = hi ? uB.z : uA.x;
                const float cmi = hi ? uB.w : uA.y;
                const float cpr = hi ? uB.x : uA.z;
                const float cpi = hi ? uB.y : uA.w;
                const float nr = cmr * ar - cmi * ai + cpr * br - cpi * bi;
                const float ni = cmr * ai + cmi * ar + cpr * bi + cpi * br;
                ar = nr; ai = ni;
            }
            const int src = l ? src1 : src0;
            ar = __shfl(ar, src);
            ai = __shfl(ai, src);
        }
    }
    Mhi[((f * 2 + 0) * 64 + lane) * 64 + bas] = f2bf(ar);
    Mhi[((f * 2 + 1) * 64 + lane) * 64 + bas] = f2bf(ai);
}

// ---------------------------------------------------------------------------
// Main: 64 patches/block, wave <-> filter f, dq-loop over all 64 d.
// R7 front-end + B-frags; R8 in-wave Z completion; 2 syncs; 6 KB zbuf
// used only for store coalescing.
// ---------------------------------------------------------------------------
__global__ __launch_bounds__(256, 4) void qconv_main(
        const float* __restrict__ x,
        const unsigned short* __restrict__ Mhi,
        float* __restrict__ out) {
    __shared__ __align__(16) unsigned short psiH[4096];   // 8 KB (64x64 bf16)
    __shared__ float zbuf[4][6][64];                      // 6 KB [f][q][p]

    const int tid  = threadIdx.x;
    const int lane = tid & 63;
    const int w    = tid >> 6;      // wave id == filter f
    const int n0   = blockIdx.x * 64;

    // ---- front-end: load, norm, bf16, stage psi (R7 verbatim) ----
    {
        const int p = tid >> 2;          // patch 0..63
        const int q = tid & 3;           // channel / k-chunk
        const int n = n0 + p;
        const int b = n / 961, pos = n - b * 961;
        const int i = pos / 31, j = pos - i * 31;
        const float* base = x + (((b * 4 + q) * 64) + i * 2) * 64 + j * 2;
        float v[16];
#pragma unroll
        for (int kh = 0; kh < 4; ++kh) {
            const float* r = base + kh * 64;
            *(f32x2*)&v[kh * 4]     = *(const f32x2*)r;
            *(f32x2*)&v[kh * 4 + 2] = *(const f32x2*)(r + 2);
        }
        float ss = 0.f;
#pragma unroll
        for (int k = 0; k < 16; ++k) ss += v[k] * v[k];
        ss += __shfl_xor(ss, 1);
        ss += __shfl_xor(ss, 2);
        const float rn = rsqrtf(ss);
        unsigned hu[8];
#pragma unroll
        for (int k2 = 0; k2 < 8; ++k2) {
            __bf16 h0 = (__bf16)(v[2 * k2] * rn);
            __bf16 h1 = (__bf16)(v[2 * k2 + 1] * rn);
            hu[k2] = (unsigned)__builtin_bit_cast(unsigned short, h0)
                   | ((unsigned)__builtin_bit_cast(unsigned short, h1) << 16);
        }
        const int s0i = p * 64 + ((2 * q) ^ (p & 7)) * 8;
        const int s1i = p * 64 + ((2 * q + 1) ^ (p & 7)) * 8;
        *(uint4*)&psiH[s0i] = make_uint4(hu[0], hu[1], hu[2], hu[3]);
        *(uint4*)&psiH[s1i] = make_uint4(hu[4], hu[5], hu[6], hu[7]);
    }

    // A-row base (verified R8 mapping): reim lane bit4, d-off lane&15, k-off hi5*8
    const int hi5   = lane >> 5;
    const int abase = ((lane >> 4) & 1) * 4096 + (lane & 15) * 64 + hi5 * 8;
    const int foff  = w * 8192;

    // prefetch A for dq=0,1 — overlaps L2 latency with the barrier
    bf16x8 Apre[2][4];
#pragma unroll
    for (int dd = 0; dd < 2; ++dd)
#pragma unroll
        for (int ks = 0; ks < 4; ++ks)
            Apre[dd][ks] = ldg8(Mhi + foff + abase + dd * 1024 + ks * 16);

    __syncthreads();

    // ---- B-fragments into registers (R7 verbatim) ----
    bf16x8 Bh[2][4];
    {
        const int pc = lane & 31;
#pragma unroll
        for (int ct = 0; ct < 2; ++ct) {
            const int pp = ct * 32 + pc;
#pragma unroll
            for (int ks = 0; ks < 4; ++ks) {
                const int idx = pp * 64 + ((2 * ks + hi5) ^ (pp & 7)) * 8;
                Bh[ct][ks] = __builtin_bit_cast(bf16x8, *(const uint4*)&psiH[idx]);
            }
        }
    }

    // ---- main: this wave handles filter f = w, all 4 d-quarters ----
    float zS[2] = {0.f, 0.f}, za[2] = {0.f, 0.f}, zbq[2] = {0.f, 0.f};
    float z2[2] = {0.f, 0.f}, z4[2] = {0.f, 0.f}, z5[2] = {0.f, 0.f};

#pragma unroll
    for (int dq = 0; dq < 4; ++dq) {
        bf16x8 A[4];
        if (dq < 2) {
#pragma unroll
            for (int ks = 0; ks < 4; ++ks) A[ks] = Apre[dq][ks];
        } else {
#pragma unroll
            for (int ks = 0; ks < 4; ++ks)
                A[ks] = ldg8(Mhi + foff + abase + dq * 1024 + ks * 16);
        }
        f32x16 C0, C1;
#pragma unroll
        for (int r = 0; r < 16; ++r) { C0[r] = 0.f; C1[r] = 0.f; }
#pragma unroll
        for (int ks = 0; ks < 4; ++ks) {
            C0 = mfma32(A[ks], Bh[0][ks], C0);
            C1 = mfma32(A[ks], Bh[1][ks], C1);
        }
#pragma unroll
        for (int ct = 0; ct < 2; ++ct) {
            const f32x16 Cv = ct ? C1 : C0;
            float P[8];
#pragma unroll
            for (int r = 0; r < 8; ++r) P[r] = Cv[r] * Cv[r] + Cv[r + 8] * Cv[r + 8];
            const float e0 = P[0] + P[1], o0 = P[0] - P[1];
            const float e1 = P[2] + P[3], o1 = P[2] - P[3];
            const float e2 = P[4] + P[5], o2 = P[4] - P[5];
            const float e3 = P[6] + P[7], o3 = P[6] - P[7];
            const float s01 = e0 + e1, s23 = e2 + e3;
            const float S  = s01 + s23;
            zS[ct]  += S;
            za[ct]  += (dq & 2) ? -S : S;               // q0: d bit5
            zbq[ct] += (dq & 1) ? -S : S;               // q1: d bit4
            z2[ct]  += s01 - s23;                       // q2: d bit3
            z4[ct]  += (e0 - e1) + (e2 - e3);           // q4: d bit1
            z5[ct]  += o0 + o1 + o2 + o3;               // q5: d bit0
        }
    }

    // ---- finish Z in-wave, park in zbuf for coalesced stores ----
#pragma unroll
    for (int ct = 0; ct < 2; ++ct) {
        float t0 = za[ct];
        float t1 = zbq[ct];
        float t2 = z2[ct];
        float t3 = hi5 ? -zS[ct] : zS[ct];              // q3: d bit2 = hi5
        float t4 = z4[ct];
        float t5 = z5[ct];
        t0 += __shfl_xor(t0, 32);
        t1 += __shfl_xor(t1, 32);
        t2 += __shfl_xor(t2, 32);
        t3 += __shfl_xor(t3, 32);
        t4 += __shfl_xor(t4, 32);
        t5 += __shfl_xor(t5, 32);
        const int pp = ct * 32 + (lane & 31);
        if (hi5 == 0) {
            zbuf[w][0][pp] = t0;
            zbuf[w][1][pp] = t1;
            zbuf[w][2][pp] = t2;
        } else {
            zbuf[w][3][pp] = t3;
            zbuf[w][4][pp] = t4;
            zbuf[w][5][pp] = t5;
        }
    }
    __syncthreads();

    // ---- coalesced store pass: 24 planes x 64-float spans ----
#pragma unroll
    for (int u = tid; u < 1536; u += 256) {
        const int m = u >> 6;          // f*6+q
        const int p = u & 63;
        const float zv = ((const float*)zbuf)[u];
        const int n = n0 + p;
        const int b = n / 961, pos = n - b * 961;
        out[(b * 24 + m) * 961 + pos] = zv;
    }
}

extern "C" void kernel_launch(void* const* d_in, const int* in_sizes, int n_in,
                              void* d_out, int out_size, void* d_ws, size_t ws_size,
                              hipStream_t stream) {
    const float* x   = (const float*)d_in[0];   // (128, 4, 64, 64)
    const float* wts = (const float*)d_in[1];   // (4, 2, 6, 3)
    float* out = (float*)d_out;                 // (128, 24, 31, 31)

    unsigned short* Mhi = (unsigned short*)d_ws;

    prep_M<<<64, 256, 0, stream>>>(wts, Mhi);

    const int npatch = 128 * 31 * 31;           // 123008 = 1922 * 64
    qconv_main<<<npatch / 64, 256, 0, stream>>>(x, Mhi, out);
}

// Round 10
// 30.217 us; speedup vs baseline: 1.8313x; 1.2818x over previous
//
#include <hip/hip_runtime.h>

typedef float f32x2 __attribute__((ext_vector_type(2)));
typedef float f32x16 __attribute__((ext_vector_type(16)));
typedef __bf16 bf16x8 __attribute__((ext_vector_type(8)));

static __device__ __forceinline__ unsigned short f2bf(float v) {
    unsigned u = __builtin_bit_cast(unsigned, v);
    unsigned r = (u + 0x7FFFu + ((u >> 16) & 1u)) >> 16;
    return (unsigned short)r;
}
static __device__ __forceinline__ bf16x8 ldg8(const unsigned short* p) {
    uint4 u = *(const uint4*)p;
    return __builtin_bit_cast(bf16x8, u);
}
static __device__ __forceinline__ f32x16 mfma32(bf16x8 a, bf16x8 b, f32x16 c) {
    return __builtin_amdgcn_mfma_f32_32x32x16_bf16(a, b, c, 0, 0, 0);
}

// ---------------------------------------------------------------------------
// prep_M: simulate the 64 basis states for each f -> M_f (64x64 complex),
// bf16, layout [f][re/im][d][k]. (verified R1-R9)
// ---------------------------------------------------------------------------
__global__ __launch_bounds__(256) void prep_M(const float* __restrict__ wts,
                                              unsigned short* __restrict__ Mhi) {
    __shared__ float gls[12][8];
    const int f = blockIdx.x >> 4;
    const int tid = threadIdx.x;
    if (tid < 12) {
        int l = tid / 6, w = tid % 6;
        const float* p = wts + ((f * 2 + l) * 6 + w) * 3;
        float phi = p[0], theta = p[1], omega = p[2];
        float c, s; sincosf(0.5f * theta, &s, &c);
        float sapo, capo, samo, camo;
        sincosf(0.5f * (phi + omega), &sapo, &capo);
        sincosf(0.5f * (phi - omega), &samo, &camo);
        float* o = gls[tid];
        o[0] =  capo * c;  o[1] = -sapo * c;
        o[2] = -camo * s;  o[3] = -samo * s;
        o[4] =  camo * s;  o[5] = -samo * s;
        o[6] =  capo * c;  o[7] =  sapo * c;
    }
    __syncthreads();

    const int lane = tid & 63;
    const int wid  = tid >> 6;
    const int bas  = (blockIdx.x & 15) * 4 + wid;

    int src0 = lane, src1 = lane;
#pragma unroll
    for (int w = 5; w >= 0; --w) { int tq = (w + 1) % 6; src0 ^= ((src0 >> (5 - w)) & 1) << (5 - tq); }
#pragma unroll
    for (int w = 5; w >= 0; --w) { int tq = (w + 2) % 6; src1 ^= ((src1 >> (5 - w)) & 1) << (5 - tq); }

    float ar = (lane == bas) ? 1.0f : 0.0f, ai = 0.0f;
#pragma unroll
    for (int rep = 0; rep < 2; ++rep) {
#pragma unroll
        for (int l = 0; l < 2; ++l) {
#pragma unroll
            for (int w = 0; w < 6; ++w) {
                const float* gp = gls[l * 6 + w];
                const float4 uA = *(const float4*)gp;
                const float4 uB = *(const float4*)(gp + 4);
                const int m = 32 >> w;
                const float br = __shfl_xor(ar, m);
                const float bi = __shfl_xor(ai, m);
                const bool hi = (lane & m) != 0;
                const float cmr = hi ? uB.z : uA.x;
                const float cmi = hi ? uB.w : uA.y;
                const float cpr = hi ? uB.x : uA.z;
                const float cpi = hi ? uB.y : uA.w;
                const float nr = cmr * ar - cmi * ai + cpr * br - cpi * bi;
                const float ni = cmr * ai + cmi * ar + cpr * bi + cpi * br;
                ar = nr; ai = ni;
            }
            const int src = l ? src1 : src0;
            ar = __shfl(ar, src);
            ai = __shfl(ai, src);
        }
    }
    Mhi[((f * 2 + 0) * 64 + lane) * 64 + bas] = f2bf(ar);
    Mhi[((f * 2 + 1) * 64 + lane) * 64 + bas] = f2bf(ai);
}

// ---------------------------------------------------------------------------
// Main: 2 tiles of 64 patches per block (tiles bid and bid+961 -> same pos,
// b+64). Waves <-> d-quarters (R7 mapping). Per f: one A fetch feeds 4
// independent MFMA chains (2 tiles x 2 col-tiles). R7 epilogue per tile.
// ---------------------------------------------------------------------------
__global__ __launch_bounds__(256, 3) void qconv_main(
        const float* __restrict__ x,
        const unsigned short* __restrict__ Mhi,
        float* __restrict__ out) {
    __shared__ __align__(16) unsigned short psiH[2][4096];   // 16 KB
    __shared__ float zbuf[2][6][4][64];                      // 12 KB [t][q][w][p]

    const int tid  = threadIdx.x;
    const int lane = tid & 63;
    const int w    = tid >> 6;
    const int bid  = blockIdx.x;

    // ---- front-end: both tiles (tile t: batch b0 + 64t, same pos/i/j) ----
    {
        const int p = tid >> 2;          // patch 0..63
        const int q = tid & 3;           // channel / k-chunk
        const int n = bid * 64 + p;
        const int b0 = n / 961, pos = n - b0 * 961;
        const int i = pos / 31, j = pos - i * 31;
        const float* base0 = x + (((b0 * 4 + q) * 64) + i * 2) * 64 + j * 2;
        float v[2][16];
#pragma unroll
        for (int t = 0; t < 2; ++t) {
            const float* base = base0 + t * 64 * 4 * 64 * 64;
#pragma unroll
            for (int kh = 0; kh < 4; ++kh) {
                const float* r = base + kh * 64;
                *(f32x2*)&v[t][kh * 4]     = *(const f32x2*)r;
                *(f32x2*)&v[t][kh * 4 + 2] = *(const f32x2*)(r + 2);
            }
        }
#pragma unroll
        for (int t = 0; t < 2; ++t) {
            float ss = 0.f;
#pragma unroll
            for (int k = 0; k < 16; ++k) ss += v[t][k] * v[t][k];
            ss += __shfl_xor(ss, 1);
            ss += __shfl_xor(ss, 2);
            const float rn = rsqrtf(ss);
            unsigned hu[8];
#pragma unroll
            for (int k2 = 0; k2 < 8; ++k2) {
                __bf16 h0 = (__bf16)(v[t][2 * k2] * rn);
                __bf16 h1 = (__bf16)(v[t][2 * k2 + 1] * rn);
                hu[k2] = (unsigned)__builtin_bit_cast(unsigned short, h0)
                       | ((unsigned)__builtin_bit_cast(unsigned short, h1) << 16);
            }
            const int s0i = p * 64 + ((2 * q) ^ (p & 7)) * 8;
            const int s1i = p * 64 + ((2 * q + 1) ^ (p & 7)) * 8;
            *(uint4*)&psiH[t][s0i] = make_uint4(hu[0], hu[1], hu[2], hu[3]);
            *(uint4*)&psiH[t][s1i] = make_uint4(hu[4], hu[5], hu[6], hu[7]);
        }
    }
    __syncthreads();

    // ---- B-fragments for both tiles (kept in registers) ----
    bf16x8 Bh[2][2][4];
    const int pc  = lane & 31;
    const int hi5 = lane >> 5;
#pragma unroll
    for (int t = 0; t < 2; ++t) {
#pragma unroll
        for (int ct = 0; ct < 2; ++ct) {
            const int pp = ct * 32 + pc;
#pragma unroll
            for (int ks = 0; ks < 4; ++ks) {
                const int idx = pp * 64 + ((2 * ks + hi5) ^ (pp & 7)) * 8;
                Bh[t][ct][ks] = __builtin_bit_cast(bf16x8, *(const uint4*)&psiH[t][idx]);
            }
        }
    }
    // no sync needed: psiH stays read-only; zbuf is separate storage

    // A-row base (R7 mapping): reim lane bit4, d = w*16+(lane&15), k-half hi5*8
    const int arow = ((lane >> 4) & 1) * 4096 + (w * 16 + (lane & 15)) * 64 + hi5 * 8;

#pragma unroll 1
    for (int f = 0; f < 4; ++f) {
        bf16x8 A[4];
#pragma unroll
        for (int ks = 0; ks < 4; ++ks) A[ks] = ldg8(Mhi + f * 8192 + arow + ks * 16);

        f32x16 C00, C01, C10, C11;
#pragma unroll
        for (int r = 0; r < 16; ++r) { C00[r] = 0.f; C01[r] = 0.f; C10[r] = 0.f; C11[r] = 0.f; }
#pragma unroll
        for (int ks = 0; ks < 4; ++ks) {
            C00 = mfma32(A[ks], Bh[0][0][ks], C00);
            C01 = mfma32(A[ks], Bh[0][1][ks], C01);
            C10 = mfma32(A[ks], Bh[1][0][ks], C10);
            C11 = mfma32(A[ks], Bh[1][1][ks], C11);
        }

        // ---- epilogue per (tile, col-tile): R7-verbatim ----
#pragma unroll
        for (int t = 0; t < 2; ++t) {
#pragma unroll
            for (int ct = 0; ct < 2; ++ct) {
                const f32x16 Cv = t ? (ct ? C11 : C10) : (ct ? C01 : C00);
                float P[8];
#pragma unroll
                for (int r = 0; r < 8; ++r) P[r] = Cv[r] * Cv[r] + Cv[r + 8] * Cv[r + 8];
                const float e0 = P[0] + P[1], o0 = P[0] - P[1];
                const float e1 = P[2] + P[3], o1 = P[2] - P[3];
                const float e2 = P[4] + P[5], o2 = P[4] - P[5];
                const float e3 = P[6] + P[7], o3 = P[6] - P[7];
                const float s01 = e0 + e1, s23 = e2 + e3;
                float S  = s01 + s23;
                float Z2 = s01 - s23;                 // sign by d&8 (r>>2)
                float Z4 = (e0 - e1) + (e2 - e3);     // sign by d&2 (r&2)
                float Z5 = o0 + o1 + o2 + o3;         // sign by d&1 (r&1)
                float Z3 = hi5 ? -S : S;              // sign by d&4 (hi5)
                S  += __shfl_xor(S, 32);
                Z2 += __shfl_xor(Z2, 32);
                Z3 += __shfl_xor(Z3, 32);
                Z4 += __shfl_xor(Z4, 32);
                Z5 += __shfl_xor(Z5, 32);
                if (lane < 32) {
                    const int pp = ct * 32 + lane;
                    zbuf[t][0][w][pp] = (w & 2) ? -S : S;   // q0: d bit5 = w>>1
                    zbuf[t][1][w][pp] = (w & 1) ? -S : S;   // q1: d bit4 = w&1
                    zbuf[t][2][w][pp] = Z2;
                    zbuf[t][3][w][pp] = Z3;
                    zbuf[t][4][w][pp] = Z4;
                    zbuf[t][5][w][pp] = Z5;
                }
            }
        }
        __syncthreads();

        // ---- combine across waves + store (both tiles, this f) ----
#pragma unroll
        for (int u = tid; u < 768; u += 256) {
            const int t   = u / 384;
            const int rem = u - t * 384;
            const int q   = rem >> 6;
            const int p   = rem & 63;
            const float* zb = &zbuf[t][q][0][p];
            const float sum = zb[0] + zb[64] + zb[128] + zb[192];
            const int nn = bid * 64 + p;
            int bb = nn / 961;
            const int pos = nn - bb * 961;
            bb += t * 64;
            out[(bb * 24 + f * 6 + q) * 961 + pos] = sum;
        }
        __syncthreads();
    }
}

extern "C" void kernel_launch(void* const* d_in, const int* in_sizes, int n_in,
                              void* d_out, int out_size, void* d_ws, size_t ws_size,
                              hipStream_t stream) {
    const float* x   = (const float*)d_in[0];   // (128, 4, 64, 64)
    const float* wts = (const float*)d_in[1];   // (4, 2, 6, 3)
    float* out = (float*)d_out;                 // (128, 24, 31, 31)

    unsigned short* Mhi = (unsigned short*)d_ws;

    prep_M<<<64, 256, 0, stream>>>(wts, Mhi);

    // 123008 patches = 961 blocks x 2 tiles x 64 patches
    qconv_main<<<961, 256, 0, stream>>>(x, Mhi, out);
}